// Round 10
// baseline (372.811 us; speedup 1.0000x reference)
//
#include <hip/hip_runtime.h>
#include <hip/hip_bf16.h>

// GCN link predictor — pipeline (R18):
//   prep:   WT1/WT2 = fp16(W^T), cursor init                        [1 launch]
//   megaA:  scatter || gemm1 rows [0,M1)    (B 2-half staged, 34KB, 4 blk/CU)
//   megaB:  csr (2 global passes, 23KB) || gemm1 rows [M1,M)
//   agg1:   hrelu = fp16(relu(di*(h1_i*di + sum_j h1_j*dj) + b1))
//   gemm2:  g2p = fp16((hrelu @ W2) * di)
//   agg2:   z = fp16(di*(g2p_i + sum_j g2p_j) + b2)
//   decode: out[e] = dot(z[a], z[b])   (4 edges/group, batched loads)
//
// Ledger (measured):
// R3/R4: gather kernels L2-miss byte-rate bound ~3.4 TB/s; agg FETCH floor
//   194MB = 8 XCD x ~24MB compulsory (R16 partition attempt: refuted, reverted).
// R12 ledger back-calc: gemm1 standalone ~71us at 1.4 TB/s. R15/R17: fusing
//   scatter/csr with gemm halves ~free, but halving gemm blocks didn't halve
//   its time -> gemm1 is issue-concurrency bound, not BW bound.
// R18 hypothesis: VGPR=92 < 128 needed for the full 16+16 load burst ->
//   compiler serializes the burst (mid-burst waitcnts); 2 blk/CU (67.5KB LDS)
//   can't cover latency. Fix: B in two 64-row halves (33.8KB -> 4 blk/CU) +
//   __launch_bounds__(256,4) (VGPR cap 128, burst fits). csr drops plds
//   staging (2 global passes) -> 23KB -> megaB also 4 blk/CU.
//   decode: 4 edges/group, 8 gathers in flight before reduce.

#define DH 128
#define BUCKET_BITS 8
#define NSH 8              // cursor shards (blockIdx & 7)
#define SUBCAP 640         // per-bucket per-shard capacity (mean 512, +5.7 sigma)
#define CAP (NSH * SUBCAP) // 5120 per bucket total
#define SEPB 4096          // edges per scatter block
#define GBM 64             // gemm rows per block
#define NPB 8              // agg nodes per block
#define BP1 264            // gemm1 B LDS row stride (halves)
#define BP2 136            // gemm2 B LDS row stride (halves)

typedef _Float16 half8 __attribute__((ext_vector_type(8)));
typedef float floatx4 __attribute__((ext_vector_type(4)));

__device__ __forceinline__ float4 h4f(uint2 uu) {
    union { uint2 u; _Float16 h[4]; } c; c.u = uu;
    return make_float4((float)c.h[0], (float)c.h[1], (float)c.h[2], (float)c.h[3]);
}

// ---------------- prep: weight transpose+cast + cursor init ----------------

__global__ __launch_bounds__(256) void prep_kernel(
    const float* __restrict__ W1, _Float16* __restrict__ WT1,
    const float* __restrict__ W2, _Float16* __restrict__ WT2,
    int* __restrict__ cursor, int nt1, int nt2) {
    __shared__ float T[32][132];
    int b = blockIdx.x, t = threadIdx.x;
    const float* W; _Float16* WT; int K, tile;
    if (b < nt1)            { W = W1; WT = WT1; K = nt1 * 32; tile = b; }
    else if (b < nt1 + nt2) { W = W2; WT = WT2; K = nt2 * 32; tile = b - nt1; }
    else {
        int i = (b - nt1 - nt2) * 256 + t;       // 16 blocks -> 4096 cursors
        cursor[i] = (i >> 3) * CAP + (i & (NSH - 1)) * SUBCAP;
        return;
    }
    int k0 = tile * 32;
    int kr = t >> 3, c0 = (t & 7) * 16;
#pragma unroll
    for (int j = 0; j < 4; j++) {
        float4 v = *(const float4*)&W[(size_t)(k0 + kr) * DH + c0 + j * 4];
        T[kr][c0 + j * 4 + 0] = v.x;
        T[kr][c0 + j * 4 + 1] = v.y;
        T[kr][c0 + j * 4 + 2] = v.z;
        T[kr][c0 + j * 4 + 3] = v.w;
    }
    __syncthreads();
    int n = t >> 1, ko = (t & 1) * 16;
    union { _Float16 h[16]; uint4 u4[2]; } p;
#pragma unroll
    for (int j = 0; j < 16; j++) p.h[j] = (_Float16)T[ko + j][n];
    *(uint4*)&WT[(size_t)n * K + k0 + ko]     = p.u4[0];
    *(uint4*)&WT[(size_t)n * K + k0 + ko + 8] = p.u4[1];
}

// ---------------- gemm1 role body (B in two 64-row halves, 33792 B LDS) ------
// h1[m][n] = fp16(sum_k x[m][k]*W1[k][n]) (unscaled). Full A K-panel burst
// (16 float4 in regs), af converted once; B half-2 prefetched during half-1.

__device__ __forceinline__ void gemm1_body(
    _Float16* Blds, const float* __restrict__ A, const _Float16* __restrict__ WT,
    _Float16* __restrict__ out, int m0, int Mlim, int K, int t) {
    int w = t >> 6, l = t & 63;
    int r = l & 15, q = l >> 4;
    int m = m0 + w * 16 + r;

    const uint4* bsrc = (const uint4*)WT;        // 4096 chunks of 16B; half = 2048
    uint4 rb[8];
#pragma unroll
    for (int i = 0; i < 8; i++) rb[i] = bsrc[i * 256 + t];

    const float* ap = A + (size_t)(m < Mlim ? m : 0) * K + q * 8;
    float4 fA[16];
#pragma unroll
    for (int i = 0; i < 8; i++) {
        fA[2 * i]     = *(const float4*)(ap + i * 32);
        fA[2 * i + 1] = *(const float4*)(ap + i * 32 + 4);
    }

#pragma unroll
    for (int i = 0; i < 8; i++) {
        int ci = i * 256 + t;                    // row = ci>>5 (0..63)
        *(uint4*)&Blds[(ci >> 5) * BP1 + (ci & 31) * 8] = rb[i];
    }
    __syncthreads();

    // prefetch half-2 of B while computing half-1
    uint4 rb2[8];
#pragma unroll
    for (int i = 0; i < 8; i++) rb2[i] = bsrc[2048 + i * 256 + t];

    half8 af[8];
#pragma unroll
    for (int kk = 0; kk < 8; kk++) {
        union { _Float16 h[8]; half8 v; } a;
        float4 f0 = fA[2 * kk], f1 = fA[2 * kk + 1];
        a.h[0] = (_Float16)f0.x; a.h[1] = (_Float16)f0.y;
        a.h[2] = (_Float16)f0.z; a.h[3] = (_Float16)f0.w;
        a.h[4] = (_Float16)f1.x; a.h[5] = (_Float16)f1.y;
        a.h[6] = (_Float16)f1.z; a.h[7] = (_Float16)f1.w;
        af[kk] = a.v;
    }

    floatx4 acc[4];
#pragma unroll
    for (int nt = 0; nt < 4; nt++) acc[nt] = (floatx4)0.f;
#pragma unroll
    for (int kk = 0; kk < 8; kk++) {
        int k0 = kk * 32;
#pragma unroll
        for (int nt = 0; nt < 4; nt++) {
            half8 bfr = *(const half8*)&Blds[(nt * 16 + r) * BP1 + k0 + q * 8];
            acc[nt] = __builtin_amdgcn_mfma_f32_16x16x32_f16(bfr, af[kk], acc[nt], 0, 0, 0);
        }
    }
    if (m < Mlim) {
#pragma unroll
        for (int nt = 0; nt < 4; nt++) {
            union { _Float16 h[4]; uint2 u; } p;
#pragma unroll
            for (int reg = 0; reg < 4; reg++)
                p.h[reg] = (_Float16)acc[nt][reg];
            *(uint2*)&out[(size_t)m * DH + nt * 16 + q * 4] = p.u;
        }
    }
    __syncthreads();
#pragma unroll
    for (int i = 0; i < 8; i++) {
        int ci = i * 256 + t;
        *(uint4*)&Blds[(ci >> 5) * BP1 + (ci & 31) * 8] = rb2[i];
    }
    __syncthreads();
#pragma unroll
    for (int nt = 0; nt < 4; nt++) acc[nt] = (floatx4)0.f;
#pragma unroll
    for (int kk = 0; kk < 8; kk++) {
        int k0 = kk * 32;
#pragma unroll
        for (int nt = 0; nt < 4; nt++) {
            half8 bfr = *(const half8*)&Blds[(nt * 16 + r) * BP1 + k0 + q * 8];
            acc[nt] = __builtin_amdgcn_mfma_f32_16x16x32_f16(bfr, af[kk], acc[nt], 0, 0, 0);
        }
    }
    if (m < Mlim) {
#pragma unroll
        for (int nt = 0; nt < 4; nt++) {
            union { _Float16 h[4]; uint2 u; } p;
#pragma unroll
            for (int reg = 0; reg < 4; reg++)
                p.h[reg] = (_Float16)acc[nt][reg];
            *(uint2*)&out[(size_t)m * DH + (nt + 4) * 16 + q * 4] = p.u;
        }
    }
}

// ---------------- megaA: scatter (blocks [0,SCB)) || gemm1 rows [0,M1) ------
// scatter: bucket = dst>>8; packed = src | (dst&255)<<17  (valid N <= 131072)

__global__ __launch_bounds__(256, 4) void megaA_kernel(
    const float* __restrict__ A, const _Float16* __restrict__ WT,
    _Float16* __restrict__ out, int M1, int K, int SCB,
    const int* __restrict__ src, const int* __restrict__ dst, int E,
    int* __restrict__ cursor, int* __restrict__ pairs) {
    __shared__ __attribute__((aligned(16))) union {
        struct { int hist[512]; int scx[512]; int rank[512]; int basep[512]; int packed[SEPB]; } s; // 24 KB
        _Float16 b[64 * BP1];                    // 33792 B
    } sm;
    int t = threadIdx.x;

    if (blockIdx.x < (unsigned)SCB) {
        // ---- scatter role ----
        int* hist = sm.s.hist; int* scx = sm.s.scx;
        int* rank = sm.s.rank; int* basep = sm.s.basep;
        int* packed = sm.s.packed;
        int e0 = blockIdx.x * SEPB;
        int sh = blockIdx.x & (NSH - 1);

        hist[t] = 0; hist[t + 256] = 0;
        rank[t] = 0; rank[t + 256] = 0;
        __syncthreads();

        int dc[SEPB / 256];
        int sv[SEPB / 256];
#pragma unroll
        for (int r = 0; r < SEPB / 256; r++) {
            int i = e0 + r * 256 + t;
            int d = -1, s = 0;
            if (i < E) { d = dst[i]; s = src[i]; atomicAdd(&hist[d >> BUCKET_BITS], 1); }
            dc[r] = d; sv[r] = s;
        }
        __syncthreads();

        scx[t] = hist[t]; scx[t + 256] = hist[t + 256];
        __syncthreads();
        for (int off = 1; off < 512; off <<= 1) {
            int a0 = (t >= off) ? scx[t - off] : 0;
            int a1 = (t + 256 >= off) ? scx[t + 256 - off] : 0;
            __syncthreads();
            scx[t] += a0; scx[t + 256] += a1;
            __syncthreads();
        }

        int c0 = hist[t], c1 = hist[t + 256];
        int g0 = c0 ? atomicAdd(&cursor[(t << 3) | sh], c0) : 0;
        int g1 = c1 ? atomicAdd(&cursor[((t + 256) << 3) | sh], c1) : 0;

#pragma unroll
        for (int r = 0; r < SEPB / 256; r++) {
            int d = dc[r];
            if (d >= 0) {
                int b = d >> BUCKET_BITS;
                int o = scx[b] - hist[b] + atomicAdd(&rank[b], 1);
                packed[o] = sv[r] | ((d & 255) << 17);
            }
        }
        basep[t] = g0; basep[t + 256] = g1;
        __syncthreads();

        int grp = t >> 4, ln = t & 15;
        for (int bb = grp; bb < 512; bb += 16) {
            int cnt = hist[bb];
            int ls = scx[bb] - cnt;
            int gs = basep[bb];
            for (int j = ln; j < cnt; j += 16)
                pairs[gs + j] = packed[ls + j];
        }
        return;
    }

    gemm1_body(sm.b, A, WT, out, (blockIdx.x - SCB) * GBM, M1, K, t);
}

// ---------------- megaB: csr (blocks [0,NB)) || gemm1 rows [M1,M) ----------
// csr role: 2 global passes over pairs (hist, then sort into LDS adjL),
// coalesced adj flush. LDS ~23.3 KB -> union 33.8 KB -> 4 blk/CU.

__global__ __launch_bounds__(256, 4) void megaB_kernel(
    const float* __restrict__ A, const _Float16* __restrict__ WT,
    _Float16* __restrict__ out, int M0, int M, int K, int NBk,
    const int* __restrict__ pairs, const int* __restrict__ cursor,
    float* __restrict__ dinv, int* __restrict__ rowptr,
    int* __restrict__ adj, int N) {
    __shared__ __attribute__((aligned(16))) union {
        struct { int adjL[CAP]; int cnt[256]; int sc[256]; int rowp[256]; } c; // 23552 B
        _Float16 b[64 * BP1];                    // 33792 B
    } sm;
    int t = threadIdx.x;

    if (blockIdx.x < (unsigned)NBk) {
        int* adjL = sm.c.adjL;
        int* cnt = sm.c.cnt; int* sc = sm.c.sc; int* rowp = sm.c.rowp;
        int b = blockIdx.x;
        int nb0 = b << BUCKET_BITS;
        int p0 = b * CAP;
        cnt[t] = 0;
        __syncthreads();
        // pass 1: histogram from global
        for (int s = 0; s < NSH; s++) {
            int q0 = p0 + s * SUBCAP;
            int q1 = cursor[(b << 3) | s];
            for (int i = q0 + t; i < q1; i += 256)
                atomicAdd(&cnt[pairs[i] >> 17], 1);
        }
        __syncthreads();
        int c = cnt[t];
        sc[t] = c;
        __syncthreads();
        for (int off = 1; off < 256; off <<= 1) {
            int u = (t >= off) ? sc[t - off] : 0;
            __syncthreads();
            sc[t] += u;
            __syncthreads();
        }
        rowp[t] = sc[t] - c;
        int node = nb0 + t;
        if (node < N) {
            rowptr[node] = p0 + sc[t] - c;
            dinv[node]   = rsqrtf((float)(c + 1));
        }
        cnt[t] = 0;
        __syncthreads();
        // pass 2: rank-sort from global into adjL
        for (int s = 0; s < NSH; s++) {
            int q0 = p0 + s * SUBCAP;
            int q1 = cursor[(b << 3) | s];
            for (int i = q0 + t; i < q1; i += 256) {
                int v = pairs[i];
                int li = v >> 17;
                int rk = atomicAdd(&cnt[li], 1);
                adjL[rowp[li] + rk] = v & 0x1FFFF;
            }
        }
        __syncthreads();
        int tot = sc[255];
        for (int j = t; j < tot; j += 256)
            adj[p0 + j] = adjL[j];
        return;
    }

    gemm1_body(sm.b, A, WT, out, M0 + (blockIdx.x - NBk) * GBM, M, K, t);
}

// ---------------- agg (templated, register gather) ----------------
// SCALED=1 (agg1): acc = h1_i*di + sum_j h1_j*dj;  out = relu(acc*di + b)
// SCALED=0 (agg2): acc = g2p_i + sum_j g2p_j;      out = acc*di + b

template <int SCALED>
__global__ __launch_bounds__(256) void agg_kernel(
    const _Float16* __restrict__ g, const int* __restrict__ rowptr,
    const float* __restrict__ dinv, const int* __restrict__ adj,
    const float* __restrict__ bias, _Float16* __restrict__ out, int N) {
    int grp = threadIdx.x >> 5;
    int l   = threadIdx.x & 31;
    int c4  = l * 4;
    int i = blockIdx.x * NPB + grp;
    if (i >= N) return;
    int r0 = rowptr[i];
    float dv = dinv[i];
    float inv2 = 1.0f / (dv * dv);
    int d = (int)(inv2 + 0.5f) - 1;              // deg from dinv (exact for small ints)
    float4 a0 = h4f(*(const uint2*)(g + (size_t)i * DH + c4));
    if (SCALED) { a0.x *= dv; a0.y *= dv; a0.z *= dv; a0.w *= dv; }
    float4 a1 = make_float4(0.f, 0.f, 0.f, 0.f);
    float4 a2 = make_float4(0.f, 0.f, 0.f, 0.f);
    float4 a3 = make_float4(0.f, 0.f, 0.f, 0.f);
    int r = 0;
    for (; r + 4 <= d; r += 4) {
        int j0 = adj[r0 + r],     j1 = adj[r0 + r + 1];
        int j2 = adj[r0 + r + 2], j3 = adj[r0 + r + 3];
        float4 v0 = h4f(*(const uint2*)(g + (size_t)j0 * DH + c4));
        float4 v1 = h4f(*(const uint2*)(g + (size_t)j1 * DH + c4));
        float4 v2 = h4f(*(const uint2*)(g + (size_t)j2 * DH + c4));
        float4 v3 = h4f(*(const uint2*)(g + (size_t)j3 * DH + c4));
        if (SCALED) {
            float d0 = dinv[j0], d1 = dinv[j1], d2 = dinv[j2], d3 = dinv[j3];
            a0.x = fmaf(v0.x, d0, a0.x); a0.y = fmaf(v0.y, d0, a0.y);
            a0.z = fmaf(v0.z, d0, a0.z); a0.w = fmaf(v0.w, d0, a0.w);
            a1.x = fmaf(v1.x, d1, a1.x); a1.y = fmaf(v1.y, d1, a1.y);
            a1.z = fmaf(v1.z, d1, a1.z); a1.w = fmaf(v1.w, d1, a1.w);
            a2.x = fmaf(v2.x, d2, a2.x); a2.y = fmaf(v2.y, d2, a2.y);
            a2.z = fmaf(v2.z, d2, a2.z); a2.w = fmaf(v2.w, d2, a2.w);
            a3.x = fmaf(v3.x, d3, a3.x); a3.y = fmaf(v3.y, d3, a3.y);
            a3.z = fmaf(v3.z, d3, a3.z); a3.w = fmaf(v3.w, d3, a3.w);
        } else {
            a0.x += v0.x; a0.y += v0.y; a0.z += v0.z; a0.w += v0.w;
            a1.x += v1.x; a1.y += v1.y; a1.z += v1.z; a1.w += v1.w;
            a2.x += v2.x; a2.y += v2.y; a2.z += v2.z; a2.w += v2.w;
            a3.x += v3.x; a3.y += v3.y; a3.z += v3.z; a3.w += v3.w;
        }
    }
    for (; r < d; r++) {
        int j = adj[r0 + r];
        float4 v = h4f(*(const uint2*)(g + (size_t)j * DH + c4));
        float dj = SCALED ? dinv[j] : 1.0f;
        a0.x = fmaf(v.x, dj, a0.x); a0.y = fmaf(v.y, dj, a0.y);
        a0.z = fmaf(v.z, dj, a0.z); a0.w = fmaf(v.w, dj, a0.w);
    }
    a0.x += a1.x + a2.x + a3.x;
    a0.y += a1.y + a2.y + a3.y;
    a0.z += a1.z + a2.z + a3.z;
    a0.w += a1.w + a2.w + a3.w;
    float4 bv = *(const float4*)(bias + c4);
    float sx = a0.x * dv + bv.x;
    float sy = a0.y * dv + bv.y;
    float sz = a0.z * dv + bv.z;
    float sw = a0.w * dv + bv.w;
    if (SCALED) {
        sx = fmaxf(sx, 0.f); sy = fmaxf(sy, 0.f);
        sz = fmaxf(sz, 0.f); sw = fmaxf(sw, 0.f);
    }
    union { _Float16 h[4]; uint2 u; } p;
    p.h[0] = (_Float16)sx; p.h[1] = (_Float16)sy;
    p.h[2] = (_Float16)sz; p.h[3] = (_Float16)sw;
    *(uint2*)(out + (size_t)i * DH + c4) = p.u;
}

// ---------------- gemm2: g2p = fp16((hrelu @ W2) * dinv), burst-issue ----------

__global__ __launch_bounds__(256) void gemm2_kernel(
    const _Float16* __restrict__ A, const _Float16* __restrict__ WT,
    const float* __restrict__ dinv, _Float16* __restrict__ out,
    int M, int K) {
    __shared__ __attribute__((aligned(16))) _Float16 Blds[128 * BP2];  // 34816 B
    int t = threadIdx.x;
    int w = t >> 6, l = t & 63;
    int r = l & 15, q = l >> 4;
    int m0 = blockIdx.x * GBM;
    int m = m0 + w * 16 + r;

    const uint4* bsrc = (const uint4*)WT;        // 32KB = 2048 chunks of 16B
    uint4 rb[8];
#pragma unroll
    for (int i = 0; i < 8; i++) rb[i] = bsrc[i * 256 + t];

    const _Float16* ap = A + (size_t)(m < M ? m : 0) * K + q * 8;
    uint4 fa[4];
#pragma unroll
    for (int i = 0; i < 4; i++) fa[i] = *(const uint4*)(ap + i * 32);

#pragma unroll
    for (int i = 0; i < 8; i++) {
        int ci = i * 256 + t;
        *(uint4*)&Blds[(ci >> 4) * BP2 + (ci & 15) * 8] = rb[i];
    }
    __syncthreads();

    floatx4 acc[8];
#pragma unroll
    for (int nt = 0; nt < 8; nt++) acc[nt] = (floatx4)0.f;

#pragma unroll
    for (int kk = 0; kk < 4; kk++) {
        union { uint4 u; half8 v; } a; a.u = fa[kk];
        int k0 = kk * 32;
#pragma unroll
        for (int nt = 0; nt < 8; nt++) {
            half8 bfr = *(const half8*)&Blds[(nt * 16 + r) * BP2 + k0 + q * 8];
            acc[nt] = __builtin_amdgcn_mfma_f32_16x16x32_f16(bfr, a.v, acc[nt], 0, 0, 0);
        }
    }
    if (m < M) {
        float dv = dinv[m];
#pragma unroll
        for (int nt = 0; nt < 8; nt++) {
            union { _Float16 h[4]; uint2 u; } p;
#pragma unroll
            for (int reg = 0; reg < 4; reg++)
                p.h[reg] = (_Float16)(acc[nt][reg] * dv);
            *(uint2*)&out[(size_t)m * DH + nt * 16 + q * 4] = p.u;
        }
    }
}

// ---------------- decode: 4 edges per 32-lane group, batched gathers ----------

__global__ __launch_bounds__(256) void decode_kernel(
    const _Float16* __restrict__ z, const int* __restrict__ ea, const int* __restrict__ eb,
    float* __restrict__ out, int EL) {
    int g = blockIdx.x * 8 + (threadIdx.x >> 5);
    int l = threadIdx.x & 31;
    int e0 = g * 4;
    if (e0 >= EL) return;
    int n = EL - e0; if (n > 4) n = 4;
    int av[4], bv[4];
#pragma unroll
    for (int k = 0; k < 4; k++) {
        int e = e0 + (k < n ? k : 0);
        av[k] = ea[e]; bv[k] = eb[e];
    }
    uint2 za[4], zb[4];
#pragma unroll
    for (int k = 0; k < 4; k++) {
        za[k] = *(const uint2*)(z + (size_t)av[k] * DH + l * 4);
        zb[k] = *(const uint2*)(z + (size_t)bv[k] * DH + l * 4);
    }
#pragma unroll
    for (int k = 0; k < 4; k++) {
        float4 va = h4f(za[k]), vb = h4f(zb[k]);
        float acc = va.x * vb.x + va.y * vb.y + va.z * vb.z + va.w * vb.w;
#pragma unroll
        for (int off = 16; off > 0; off >>= 1)
            acc += __shfl_down(acc, off, 32);
        if (l == 0 && k < n) out[e0 + k] = acc;
    }
}

// ---------------- Launch ----------------

extern "C" void kernel_launch(void* const* d_in, const int* in_sizes, int n_in,
                              void* d_out, int out_size, void* d_ws, size_t ws_size,
                              hipStream_t stream) {
    const float* x   = (const float*)d_in[0];
    const int*   ei  = (const int*)d_in[1];
    const int*   eli = (const int*)d_in[2];
    const float* W1  = (const float*)d_in[3];
    const float* b1  = (const float*)d_in[4];
    const float* W2  = (const float*)d_in[5];
    const float* b2  = (const float*)d_in[6];
    float* out = (float*)d_out;

    int DHv = in_sizes[4];                 // 128
    int DIN = in_sizes[3] / DHv;           // 256
    int N   = in_sizes[0] / DIN;           // 100000
    int E   = in_sizes[1] / 2;             // 1600000
    int EL  = in_sizes[2] / 2;             // 200000
    const int* src = ei;
    const int* dst = ei + E;
    const int* ea = eli;
    const int* eb = eli + EL;

    int NB = (N + 255) >> BUCKET_BITS;     // 391 buckets
    int SCB = (E + SEPB - 1) / SEPB;       // 391 scatter blocks
    int GB = (N + GBM - 1) / GBM;          // 1563 gemm blocks total
    int GBA = GB / 2;                      // 781 gemm blocks in megaA
    int M1 = GBA * GBM;                    // 49984 rows in megaA
    int GBB = GB - GBA;                    // 782 gemm blocks in megaB

    // workspace carve-up (256B aligned)
    char* ws = (char*)d_ws;
    size_t off = 0;
    auto alloc = [&](size_t bytes) {
        void* p = ws + off;
        off += (bytes + 255) & ~(size_t)255;
        return p;
    };
    int*      cursor = (int*)alloc(4096 * 4);
    float*    dinv   = (float*)alloc((size_t)N * 4);
    int*      rowptr = (int*)alloc((size_t)N * 4);
    int*      pairs  = (int*)alloc((size_t)NB * CAP * 4);      // bucketed, with gaps
    int*      adj    = (int*)alloc((size_t)NB * CAP * 4);      // bucketed CSR
    _Float16* WT1    = (_Float16*)alloc((size_t)DIN * DHv * 2);
    _Float16* WT2    = (_Float16*)alloc((size_t)DHv * DHv * 2);
    _Float16* gbuf   = (_Float16*)alloc((size_t)N * DH * 2);   // h1 -> g2p
    _Float16* hbuf   = (_Float16*)alloc((size_t)N * DH * 2);   // hrelu -> z

    int nt1 = DIN / 32, nt2 = DHv / 32;
    // prep: WT1, WT2, cursor
    prep_kernel<<<nt1 + nt2 + 16, 256, 0, stream>>>(W1, WT1, W2, WT2, cursor, nt1, nt2);
    // megaA: scatter || gemm1 rows [0,M1)
    megaA_kernel<<<SCB + GBA, 256, 0, stream>>>(x, WT1, gbuf, M1, DIN, SCB,
                                                src, dst, E, cursor, pairs);
    // megaB: csr || gemm1 rows [M1,N)
    megaB_kernel<<<NB + GBB, 256, 0, stream>>>(x, WT1, gbuf, M1, N, DIN, NB,
                                               pairs, cursor, dinv, rowptr, adj, N);
    // agg1: hrelu (per-edge dinv, relu)
    agg_kernel<1><<<(N + NPB - 1) / NPB, 256, 0, stream>>>(gbuf, rowptr, dinv, adj, b1, hbuf, N);
    // gemm2: g2p = fp16((hrelu @ W2) * dinv)
    gemm2_kernel<<<GB, 256, 0, stream>>>(hbuf, WT2, dinv, gbuf, N, DHv);
    // agg2: z (pure sum)
    agg_kernel<0><<<(N + NPB - 1) / NPB, 256, 0, stream>>>(gbuf, rowptr, dinv, adj, b2, hbuf, N);
    // decode (4 edges/group)
    decode_kernel<<<(EL + 31) / 32, 256, 0, stream>>>(hbuf, ea, eb, out, EL);
}

// Round 11
// 357.472 us; speedup vs baseline: 1.0429x; 1.0429x over previous
//
#include <hip/hip_runtime.h>
#include <hip/hip_bf16.h>

// GCN link predictor — pipeline (R19):
//   prep:   WT1/WT2 = fp16(W^T), cursor init                        [1 launch]
//   megaA:  scatter || gemm1 rows [0,M1)   (R17 body, launch_bounds(256,2))
//   megaB:  csr || gemm1 rows [M1,M)       (R17 body, launch_bounds(256,2))
//   agg1:   hrelu = fp16(relu(di*(h1_i*di + sum_j h1_j*dj) + b1))
//   gemm2:  g2p = fp16((hrelu @ W2) * di)
//   agg2:   z = fp16(di*(g2p_i + sum_j g2p_j) + b2)
//   decode: out[e] = dot(z[a], z[b])   (4 edges/group, 8 gathers in flight)
//
// Ledger (measured):
// R3/R4: gather kernels L2-miss byte-rate bound ~3.4 TB/s; agg FETCH floor
//   194MB = 8 XCD x ~24MB compulsory (R16 partition attempt refuted).
// R15/R17: best = 361; front gemm1 ~65-70us across THREE structures, ~4x its
//   ~17us L3-stream floor; MfmaUtil 3.5%, VALU 7% -> pure latency.
// R18: 2-half B staging + launch_bounds(256,4) REGRESSED (+12us): extra
//   barriers cost more than 4 blk/CU buys (occupancy branch dead). Register
//   branch untested: cap 128 < ~140 needed -> burst still serialized.
// R19: launch_bounds(256,2) -> VGPR cap 256; full 16+16 load burst stays in
//   flight, ONE wait. Residency still 2 blk/CU (LDS 67.5KB, same as R15/R17)
//   -> isolates MLP. decode: 4 edges/group (R18 piece, safe). If VGPR>130
//   but megas unchanged -> MLP theory dead, declare structure-optimal.

#define DH 128
#define BUCKET_BITS 8
#define NSH 8              // cursor shards (blockIdx & 7)
#define SUBCAP 640         // per-bucket per-shard capacity (mean 512, +5.7 sigma)
#define CAP (NSH * SUBCAP) // 5120 per bucket total
#define SEPB 4096          // edges per scatter block
#define GBM 64             // gemm rows per block
#define NPB 8              // agg nodes per block
#define BP1 264            // gemm1 B LDS row stride (halves)
#define BP2 136            // gemm2 B LDS row stride (halves)

typedef _Float16 half8 __attribute__((ext_vector_type(8)));
typedef float floatx4 __attribute__((ext_vector_type(4)));

__device__ __forceinline__ float4 h4f(uint2 uu) {
    union { uint2 u; _Float16 h[4]; } c; c.u = uu;
    return make_float4((float)c.h[0], (float)c.h[1], (float)c.h[2], (float)c.h[3]);
}

// ---------------- prep: weight transpose+cast + cursor init ----------------

__global__ __launch_bounds__(256) void prep_kernel(
    const float* __restrict__ W1, _Float16* __restrict__ WT1,
    const float* __restrict__ W2, _Float16* __restrict__ WT2,
    int* __restrict__ cursor, int nt1, int nt2) {
    __shared__ float T[32][132];
    int b = blockIdx.x, t = threadIdx.x;
    const float* W; _Float16* WT; int K, tile;
    if (b < nt1)            { W = W1; WT = WT1; K = nt1 * 32; tile = b; }
    else if (b < nt1 + nt2) { W = W2; WT = WT2; K = nt2 * 32; tile = b - nt1; }
    else {
        int i = (b - nt1 - nt2) * 256 + t;       // 16 blocks -> 4096 cursors
        cursor[i] = (i >> 3) * CAP + (i & (NSH - 1)) * SUBCAP;
        return;
    }
    int k0 = tile * 32;
    int kr = t >> 3, c0 = (t & 7) * 16;
#pragma unroll
    for (int j = 0; j < 4; j++) {
        float4 v = *(const float4*)&W[(size_t)(k0 + kr) * DH + c0 + j * 4];
        T[kr][c0 + j * 4 + 0] = v.x;
        T[kr][c0 + j * 4 + 1] = v.y;
        T[kr][c0 + j * 4 + 2] = v.z;
        T[kr][c0 + j * 4 + 3] = v.w;
    }
    __syncthreads();
    int n = t >> 1, ko = (t & 1) * 16;
    union { _Float16 h[16]; uint4 u4[2]; } p;
#pragma unroll
    for (int j = 0; j < 16; j++) p.h[j] = (_Float16)T[ko + j][n];
    *(uint4*)&WT[(size_t)n * K + k0 + ko]     = p.u4[0];
    *(uint4*)&WT[(size_t)n * K + k0 + ko + 8] = p.u4[1];
}

// ---------------- gemm1 role body (R17: full 64KB B, single stage) ----------
// h1[m][n] = fp16(sum_k x[m][k]*W1[k][n]) (unscaled), R10 burst form.

__device__ __forceinline__ void gemm1_body(
    _Float16* Blds, const float* __restrict__ A, const _Float16* __restrict__ WT,
    _Float16* __restrict__ out, int m0, int Mlim, int K, int t) {
    int w = t >> 6, l = t & 63;
    int r = l & 15, q = l >> 4;
    int m = m0 + w * 16 + r;

    const uint4* bsrc = (const uint4*)WT;        // 64KB = 4096 chunks of 16B
    uint4 rb[16];
#pragma unroll
    for (int i = 0; i < 16; i++) rb[i] = bsrc[i * 256 + t];

    const float* ap = A + (size_t)(m < Mlim ? m : 0) * K + q * 8;
    float4 fA[16];
#pragma unroll
    for (int i = 0; i < 8; i++) {
        fA[2 * i]     = *(const float4*)(ap + i * 32);
        fA[2 * i + 1] = *(const float4*)(ap + i * 32 + 4);
    }

#pragma unroll
    for (int i = 0; i < 16; i++) {
        int ci = i * 256 + t;
        *(uint4*)&Blds[(ci >> 5) * BP1 + (ci & 31) * 8] = rb[i];
    }
    __syncthreads();

    floatx4 acc[8];
#pragma unroll
    for (int nt = 0; nt < 8; nt++) acc[nt] = (floatx4)0.f;

#pragma unroll
    for (int kk = 0; kk < 8; kk++) {
        union { _Float16 h[8]; half8 v; } a;
        float4 f0 = fA[2 * kk], f1 = fA[2 * kk + 1];
        a.h[0] = (_Float16)f0.x; a.h[1] = (_Float16)f0.y;
        a.h[2] = (_Float16)f0.z; a.h[3] = (_Float16)f0.w;
        a.h[4] = (_Float16)f1.x; a.h[5] = (_Float16)f1.y;
        a.h[6] = (_Float16)f1.z; a.h[7] = (_Float16)f1.w;
        int k0 = kk * 32;
#pragma unroll
        for (int nt = 0; nt < 8; nt++) {
            half8 bfr = *(const half8*)&Blds[(nt * 16 + r) * BP1 + k0 + q * 8];
            acc[nt] = __builtin_amdgcn_mfma_f32_16x16x32_f16(bfr, a.v, acc[nt], 0, 0, 0);
        }
    }
    if (m < Mlim) {
#pragma unroll
        for (int nt = 0; nt < 8; nt++) {
            union { _Float16 h[4]; uint2 u; } p;
#pragma unroll
            for (int reg = 0; reg < 4; reg++)
                p.h[reg] = (_Float16)acc[nt][reg];
            *(uint2*)&out[(size_t)m * DH + nt * 16 + q * 4] = p.u;
        }
    }
}

// ---------------- megaA: scatter (blocks [0,SCB)) || gemm1 rows [0,M1) ------
// scatter: bucket = dst>>8; packed = src | (dst&255)<<17  (valid N <= 131072)

__global__ __launch_bounds__(256, 2) void megaA_kernel(
    const float* __restrict__ A, const _Float16* __restrict__ WT,
    _Float16* __restrict__ out, int M1, int K, int SCB,
    const int* __restrict__ src, const int* __restrict__ dst, int E,
    int* __restrict__ cursor, int* __restrict__ pairs) {
    __shared__ __attribute__((aligned(16))) union {
        struct { int hist[512]; int scx[512]; int rank[512]; int basep[512]; int packed[SEPB]; } s; // 24 KB
        _Float16 b[128 * BP1];                   // 67584 B
    } sm;
    int t = threadIdx.x;

    if (blockIdx.x < (unsigned)SCB) {
        // ---- scatter role ----
        int* hist = sm.s.hist; int* scx = sm.s.scx;
        int* rank = sm.s.rank; int* basep = sm.s.basep;
        int* packed = sm.s.packed;
        int e0 = blockIdx.x * SEPB;
        int sh = blockIdx.x & (NSH - 1);

        hist[t] = 0; hist[t + 256] = 0;
        rank[t] = 0; rank[t + 256] = 0;
        __syncthreads();

        int dc[SEPB / 256];
        int sv[SEPB / 256];
#pragma unroll
        for (int r = 0; r < SEPB / 256; r++) {
            int i = e0 + r * 256 + t;
            int d = -1, s = 0;
            if (i < E) { d = dst[i]; s = src[i]; atomicAdd(&hist[d >> BUCKET_BITS], 1); }
            dc[r] = d; sv[r] = s;
        }
        __syncthreads();

        scx[t] = hist[t]; scx[t + 256] = hist[t + 256];
        __syncthreads();
        for (int off = 1; off < 512; off <<= 1) {
            int a0 = (t >= off) ? scx[t - off] : 0;
            int a1 = (t + 256 >= off) ? scx[t + 256 - off] : 0;
            __syncthreads();
            scx[t] += a0; scx[t + 256] += a1;
            __syncthreads();
        }

        int c0 = hist[t], c1 = hist[t + 256];
        int g0 = c0 ? atomicAdd(&cursor[(t << 3) | sh], c0) : 0;
        int g1 = c1 ? atomicAdd(&cursor[((t + 256) << 3) | sh], c1) : 0;

#pragma unroll
        for (int r = 0; r < SEPB / 256; r++) {
            int d = dc[r];
            if (d >= 0) {
                int b = d >> BUCKET_BITS;
                int o = scx[b] - hist[b] + atomicAdd(&rank[b], 1);
                packed[o] = sv[r] | ((d & 255) << 17);
            }
        }
        basep[t] = g0; basep[t + 256] = g1;
        __syncthreads();

        int grp = t >> 4, ln = t & 15;
        for (int bb = grp; bb < 512; bb += 16) {
            int cnt = hist[bb];
            int ls = scx[bb] - cnt;
            int gs = basep[bb];
            for (int j = ln; j < cnt; j += 16)
                pairs[gs + j] = packed[ls + j];
        }
        return;
    }

    gemm1_body(sm.b, A, WT, out, (blockIdx.x - SCB) * GBM, M1, K, t);
}

// ---------------- megaB: csr (blocks [0,NB)) || gemm1 rows [M1,M) ----------

__global__ __launch_bounds__(256, 2) void megaB_kernel(
    const float* __restrict__ A, const _Float16* __restrict__ WT,
    _Float16* __restrict__ out, int M0, int M, int K, int NBk,
    const int* __restrict__ pairs, const int* __restrict__ cursor,
    float* __restrict__ dinv, int* __restrict__ rowptr,
    int* __restrict__ adj, int N) {
    __shared__ __attribute__((aligned(16))) union {
        struct { int plds[CAP]; int adjL[CAP]; int cnt[256]; int sc[256]; int rowp[256]; int soff[NSH + 1]; } c; // ~44 KB
        _Float16 b[128 * BP1];                   // 67584 B
    } sm;
    int t = threadIdx.x;

    if (blockIdx.x < (unsigned)NBk) {
        // ---- csr role: stage -> histogram -> sort -> coalesced flush ----
        int* plds = sm.c.plds; int* adjL = sm.c.adjL;
        int* cnt = sm.c.cnt; int* sc = sm.c.sc;
        int* rowp = sm.c.rowp; int* soff = sm.c.soff;
        int b = blockIdx.x;
        int nb0 = b << BUCKET_BITS;
        int p0 = b * CAP;

        if (t < NSH) soff[t + 1] = cursor[(b << 3) | t] - (p0 + t * SUBCAP);
        cnt[t] = 0;
        __syncthreads();
        if (t == 0) {
            soff[0] = 0;
#pragma unroll
            for (int s = 0; s < NSH; s++) soff[s + 1] += soff[s];
        }
        __syncthreads();

        for (int s = 0; s < NSH; s++) {
            int q0 = p0 + s * SUBCAP;
            int o = soff[s];
            int c = soff[s + 1] - o;
            for (int i = t; i < c; i += 256) plds[o + i] = pairs[q0 + i];
        }
        __syncthreads();
        int tot = soff[NSH];

        for (int i = t; i < tot; i += 256) atomicAdd(&cnt[plds[i] >> 17], 1);
        __syncthreads();
        int c = cnt[t];
        sc[t] = c;
        __syncthreads();
        for (int off = 1; off < 256; off <<= 1) {
            int u = (t >= off) ? sc[t - off] : 0;
            __syncthreads();
            sc[t] += u;
            __syncthreads();
        }
        rowp[t] = sc[t] - c;
        int node = nb0 + t;
        if (node < N) {
            rowptr[node] = p0 + sc[t] - c;
            dinv[node]   = rsqrtf((float)(c + 1));
        }
        cnt[t] = 0;
        __syncthreads();

        for (int i = t; i < tot; i += 256) {
            int v = plds[i];
            int li = v >> 17;
            int rk = atomicAdd(&cnt[li], 1);
            adjL[rowp[li] + rk] = v & 0x1FFFF;
        }
        __syncthreads();

        for (int j = t; j < tot; j += 256)
            adj[p0 + j] = adjL[j];
        return;
    }

    gemm1_body(sm.b, A, WT, out, M0 + (blockIdx.x - NBk) * GBM, M, K, t);
}

// ---------------- agg (templated, register gather) ----------------
// SCALED=1 (agg1): acc = h1_i*di + sum_j h1_j*dj;  out = relu(acc*di + b)
// SCALED=0 (agg2): acc = g2p_i + sum_j g2p_j;      out = acc*di + b

template <int SCALED>
__global__ __launch_bounds__(256) void agg_kernel(
    const _Float16* __restrict__ g, const int* __restrict__ rowptr,
    const float* __restrict__ dinv, const int* __restrict__ adj,
    const float* __restrict__ bias, _Float16* __restrict__ out, int N) {
    int grp = threadIdx.x >> 5;
    int l   = threadIdx.x & 31;
    int c4  = l * 4;
    int i = blockIdx.x * NPB + grp;
    if (i >= N) return;
    int r0 = rowptr[i];
    float dv = dinv[i];
    float inv2 = 1.0f / (dv * dv);
    int d = (int)(inv2 + 0.5f) - 1;              // deg from dinv (exact for small ints)
    float4 a0 = h4f(*(const uint2*)(g + (size_t)i * DH + c4));
    if (SCALED) { a0.x *= dv; a0.y *= dv; a0.z *= dv; a0.w *= dv; }
    float4 a1 = make_float4(0.f, 0.f, 0.f, 0.f);
    float4 a2 = make_float4(0.f, 0.f, 0.f, 0.f);
    float4 a3 = make_float4(0.f, 0.f, 0.f, 0.f);
    int r = 0;
    for (; r + 4 <= d; r += 4) {
        int j0 = adj[r0 + r],     j1 = adj[r0 + r + 1];
        int j2 = adj[r0 + r + 2], j3 = adj[r0 + r + 3];
        float4 v0 = h4f(*(const uint2*)(g + (size_t)j0 * DH + c4));
        float4 v1 = h4f(*(const uint2*)(g + (size_t)j1 * DH + c4));
        float4 v2 = h4f(*(const uint2*)(g + (size_t)j2 * DH + c4));
        float4 v3 = h4f(*(const uint2*)(g + (size_t)j3 * DH + c4));
        if (SCALED) {
            float d0 = dinv[j0], d1 = dinv[j1], d2 = dinv[j2], d3 = dinv[j3];
            a0.x = fmaf(v0.x, d0, a0.x); a0.y = fmaf(v0.y, d0, a0.y);
            a0.z = fmaf(v0.z, d0, a0.z); a0.w = fmaf(v0.w, d0, a0.w);
            a1.x = fmaf(v1.x, d1, a1.x); a1.y = fmaf(v1.y, d1, a1.y);
            a1.z = fmaf(v1.z, d1, a1.z); a1.w = fmaf(v1.w, d1, a1.w);
            a2.x = fmaf(v2.x, d2, a2.x); a2.y = fmaf(v2.y, d2, a2.y);
            a2.z = fmaf(v2.z, d2, a2.z); a2.w = fmaf(v2.w, d2, a2.w);
            a3.x = fmaf(v3.x, d3, a3.x); a3.y = fmaf(v3.y, d3, a3.y);
            a3.z = fmaf(v3.z, d3, a3.z); a3.w = fmaf(v3.w, d3, a3.w);
        } else {
            a0.x += v0.x; a0.y += v0.y; a0.z += v0.z; a0.w += v0.w;
            a1.x += v1.x; a1.y += v1.y; a1.z += v1.z; a1.w += v1.w;
            a2.x += v2.x; a2.y += v2.y; a2.z += v2.z; a2.w += v2.w;
            a3.x += v3.x; a3.y += v3.y; a3.z += v3.z; a3.w += v3.w;
        }
    }
    for (; r < d; r++) {
        int j = adj[r0 + r];
        float4 v = h4f(*(const uint2*)(g + (size_t)j * DH + c4));
        float dj = SCALED ? dinv[j] : 1.0f;
        a0.x = fmaf(v.x, dj, a0.x); a0.y = fmaf(v.y, dj, a0.y);
        a0.z = fmaf(v.z, dj, a0.z); a0.w = fmaf(v.w, dj, a0.w);
    }
    a0.x += a1.x + a2.x + a3.x;
    a0.y += a1.y + a2.y + a3.y;
    a0.z += a1.z + a2.z + a3.z;
    a0.w += a1.w + a2.w + a3.w;
    float4 bv = *(const float4*)(bias + c4);
    float sx = a0.x * dv + bv.x;
    float sy = a0.y * dv + bv.y;
    float sz = a0.z * dv + bv.z;
    float sw = a0.w * dv + bv.w;
    if (SCALED) {
        sx = fmaxf(sx, 0.f); sy = fmaxf(sy, 0.f);
        sz = fmaxf(sz, 0.f); sw = fmaxf(sw, 0.f);
    }
    union { _Float16 h[4]; uint2 u; } p;
    p.h[0] = (_Float16)sx; p.h[1] = (_Float16)sy;
    p.h[2] = (_Float16)sz; p.h[3] = (_Float16)sw;
    *(uint2*)(out + (size_t)i * DH + c4) = p.u;
}

// ---------------- gemm2: g2p = fp16((hrelu @ W2) * dinv), burst-issue ----------

__global__ __launch_bounds__(256) void gemm2_kernel(
    const _Float16* __restrict__ A, const _Float16* __restrict__ WT,
    const float* __restrict__ dinv, _Float16* __restrict__ out,
    int M, int K) {
    __shared__ __attribute__((aligned(16))) _Float16 Blds[128 * BP2];  // 34816 B
    int t = threadIdx.x;
    int w = t >> 6, l = t & 63;
    int r = l & 15, q = l >> 4;
    int m0 = blockIdx.x * GBM;
    int m = m0 + w * 16 + r;

    const uint4* bsrc = (const uint4*)WT;        // 32KB = 2048 chunks of 16B
    uint4 rb[8];
#pragma unroll
    for (int i = 0; i < 8; i++) rb[i] = bsrc[i * 256 + t];

    const _Float16* ap = A + (size_t)(m < M ? m : 0) * K + q * 8;
    uint4 fa[4];
#pragma unroll
    for (int i = 0; i < 4; i++) fa[i] = *(const uint4*)(ap + i * 32);

#pragma unroll
    for (int i = 0; i < 8; i++) {
        int ci = i * 256 + t;
        *(uint4*)&Blds[(ci >> 4) * BP2 + (ci & 15) * 8] = rb[i];
    }
    __syncthreads();

    floatx4 acc[8];
#pragma unroll
    for (int nt = 0; nt < 8; nt++) acc[nt] = (floatx4)0.f;

#pragma unroll
    for (int kk = 0; kk < 4; kk++) {
        union { uint4 u; half8 v; } a; a.u = fa[kk];
        int k0 = kk * 32;
#pragma unroll
        for (int nt = 0; nt < 8; nt++) {
            half8 bfr = *(const half8*)&Blds[(nt * 16 + r) * BP2 + k0 + q * 8];
            acc[nt] = __builtin_amdgcn_mfma_f32_16x16x32_f16(bfr, a.v, acc[nt], 0, 0, 0);
        }
    }
    if (m < M) {
        float dv = dinv[m];
#pragma unroll
        for (int nt = 0; nt < 8; nt++) {
            union { _Float16 h[4]; uint2 u; } p;
#pragma unroll
            for (int reg = 0; reg < 4; reg++)
                p.h[reg] = (_Float16)(acc[nt][reg] * dv);
            *(uint2*)&out[(size_t)m * DH + nt * 16 + q * 4] = p.u;
        }
    }
}

// ---------------- decode: 4 edges per 32-lane group, batched gathers ----------

__global__ __launch_bounds__(256) void decode_kernel(
    const _Float16* __restrict__ z, const int* __restrict__ ea, const int* __restrict__ eb,
    float* __restrict__ out, int EL) {
    int g = blockIdx.x * 8 + (threadIdx.x >> 5);
    int l = threadIdx.x & 31;
    int e0 = g * 4;
    if (e0 >= EL) return;
    int n = EL - e0; if (n > 4) n = 4;
    int av[4], bv[4];
#pragma unroll
    for (int k = 0; k < 4; k++) {
        int e = e0 + (k < n ? k : 0);
        av[k] = ea[e]; bv[k] = eb[e];
    }
    uint2 za[4], zb[4];
#pragma unroll
    for (int k = 0; k < 4; k++) {
        za[k] = *(const uint2*)(z + (size_t)av[k] * DH + l * 4);
        zb[k] = *(const uint2*)(z + (size_t)bv[k] * DH + l * 4);
    }
#pragma unroll
    for (int k = 0; k < 4; k++) {
        float4 va = h4f(za[k]), vb = h4f(zb[k]);
        float acc = va.x * vb.x + va.y * vb.y + va.z * vb.z + va.w * vb.w;
#pragma unroll
        for (int off = 16; off > 0; off >>= 1)
            acc += __shfl_down(acc, off, 32);
        if (l == 0 && k < n) out[e0 + k] = acc;
    }
}

// ---------------- Launch ----------------

extern "C" void kernel_launch(void* const* d_in, const int* in_sizes, int n_in,
                              void* d_out, int out_size, void* d_ws, size_t ws_size,
                              hipStream_t stream) {
    const float* x   = (const float*)d_in[0];
    const int*   ei  = (const int*)d_in[1];
    const int*   eli = (const int*)d_in[2];
    const float* W1  = (const float*)d_in[3];
    const float* b1  = (const float*)d_in[4];
    const float* W2  = (const float*)d_in[5];
    const float* b2  = (const float*)d_in[6];
    float* out = (float*)d_out;

    int DHv = in_sizes[4];                 // 128
    int DIN = in_sizes[3] / DHv;           // 256
    int N   = in_sizes[0] / DIN;           // 100000
    int E   = in_sizes[1] / 2;             // 1600000
    int EL  = in_sizes[2] / 2;             // 200000
    const int* src = ei;
    const int* dst = ei + E;
    const int* ea = eli;
    const int* eb = eli + EL;

    int NB = (N + 255) >> BUCKET_BITS;     // 391 buckets
    int SCB = (E + SEPB - 1) / SEPB;       // 391 scatter blocks
    int GB = (N + GBM - 1) / GBM;          // 1563 gemm blocks total
    int GBA = GB / 2;                      // 781 gemm blocks in megaA
    int M1 = GBA * GBM;                    // 49984 rows in megaA
    int GBB = GB - GBA;                    // 782 gemm blocks in megaB

    // workspace carve-up (256B aligned)
    char* ws = (char*)d_ws;
    size_t off = 0;
    auto alloc = [&](size_t bytes) {
        void* p = ws + off;
        off += (bytes + 255) & ~(size_t)255;
        return p;
    };
    int*      cursor = (int*)alloc(4096 * 4);
    float*    dinv   = (float*)alloc((size_t)N * 4);
    int*      rowptr = (int*)alloc((size_t)N * 4);
    int*      pairs  = (int*)alloc((size_t)NB * CAP * 4);      // bucketed, with gaps
    int*      adj    = (int*)alloc((size_t)NB * CAP * 4);      // bucketed CSR
    _Float16* WT1    = (_Float16*)alloc((size_t)DIN * DHv * 2);
    _Float16* WT2    = (_Float16*)alloc((size_t)DHv * DHv * 2);
    _Float16* gbuf   = (_Float16*)alloc((size_t)N * DH * 2);   // h1 -> g2p
    _Float16* hbuf   = (_Float16*)alloc((size_t)N * DH * 2);   // hrelu -> z

    int nt1 = DIN / 32, nt2 = DHv / 32;
    // prep: WT1, WT2, cursor
    prep_kernel<<<nt1 + nt2 + 16, 256, 0, stream>>>(W1, WT1, W2, WT2, cursor, nt1, nt2);
    // megaA: scatter || gemm1 rows [0,M1)
    megaA_kernel<<<SCB + GBA, 256, 0, stream>>>(x, WT1, gbuf, M1, DIN, SCB,
                                                src, dst, E, cursor, pairs);
    // megaB: csr || gemm1 rows [M1,N)
    megaB_kernel<<<NB + GBB, 256, 0, stream>>>(x, WT1, gbuf, M1, N, DIN, NB,
                                               pairs, cursor, dinv, rowptr, adj, N);
    // agg1: hrelu (per-edge dinv, relu)
    agg_kernel<1><<<(N + NPB - 1) / NPB, 256, 0, stream>>>(gbuf, rowptr, dinv, adj, b1, hbuf, N);
    // gemm2: g2p = fp16((hrelu @ W2) * dinv)
    gemm2_kernel<<<GB, 256, 0, stream>>>(hbuf, WT2, dinv, gbuf, N, DHv);
    // agg2: z (pure sum)
    agg_kernel<0><<<(N + NPB - 1) / NPB, 256, 0, stream>>>(gbuf, rowptr, dinv, adj, b2, hbuf, N);
    // decode (4 edges/group)
    decode_kernel<<<(EL + 31) / 32, 256, 0, stream>>>(hbuf, ea, eb, out, EL);
}